// Round 21
// baseline (517.720 us; speedup 1.0000x reference)
//
#include <hip/hip_runtime.h>
#include <hip/hip_bf16.h>

typedef __hip_bfloat16 bf16;
typedef __attribute__((ext_vector_type(8))) short short8;
typedef __attribute__((ext_vector_type(4))) short short4v;
typedef __attribute__((ext_vector_type(4))) float f32x4;

#define KN 8384
#define KNPAD 8448
#define KE 50000
#define NBIG 4480    /* 4096 feat + 256 qk + 128 elr(pad) = 35*128 */

__device__ __forceinline__ float toF(float v){ return v; }
__device__ __forceinline__ float toF(bf16 v){ return __bfloat162float(v); }
__device__ __forceinline__ float b2f(short u){ return __uint_as_float(((unsigned int)(unsigned short)u) << 16); }
__device__ __forceinline__ void stor(float* p, float v){ *p = v; }
__device__ __forceinline__ void stor(bf16* p, float v){ *p = __float2bfloat16(v); }

__device__ __forceinline__ void glds16(const bf16* g, bf16* l){
  __builtin_amdgcn_global_load_lds(
      (const __attribute__((address_space(1))) unsigned int*)(g),
      (__attribute__((address_space(3))) unsigned int*)(l), 16, 0, 0);
}

// ---------------- MFMA GEMM: 3-buf glds pipeline, vmcnt(4), XCD-chunked swizzle ----------------
template<typename TC>
__global__ __launch_bounds__(256)
void gemm_mfma_bt(const bf16* __restrict__ A, const bf16* __restrict__ BT,
                  const float* __restrict__ bias, TC* __restrict__ C,
                  int M, int N, int K, int ldc, int nbx)
{
  __shared__ bf16 As[3][128 * 32];
  __shared__ bf16 Bs[3][128 * 32];
  const int nwg = gridDim.x;
  const int q = nwg >> 3, r = nwg & 7;
  const int xcd = blockIdx.x & 7, idx = blockIdx.x >> 3;
  const int sw = (xcd < r) ? xcd * (q + 1) + idx : r * (q + 1) + (xcd - r) * q + idx;
  const int bn = (sw % nbx) * 128, bm = (sw / nbx) * 128;
  const int tid = threadIdx.x;
  const int w = tid >> 6, l = tid & 63;
  const int wr = (w >> 1) * 64, wc = (w & 1) * 64;
  const int lr = l & 15;
  int rS[2], lqS[2];
  #pragma unroll
  for (int i = 0; i < 2; i++){
    rS[i] = w * 32 + i * 16 + (l >> 2);
    lqS[i] = (l & 3) ^ ((rS[i] >> 1) & 3);
  }
  const bf16* gA0 = A  + (size_t)(bm + rS[0]) * K + lqS[0] * 8;
  const bf16* gA1 = A  + (size_t)(bm + rS[1]) * K + lqS[1] * 8;
  const bf16* gB0 = BT + (size_t)(bn + rS[0]) * K + lqS[0] * 8;
  const bf16* gB1 = BT + (size_t)(bn + rS[1]) * K + lqS[1] * 8;
  const int nt = K >> 5;
  auto issue = [&](int t){
    int b = t - (t / 3) * 3;
    int k0 = t << 5;
    glds16(gA0 + k0, &As[b][w * 1024]);
    glds16(gA1 + k0, &As[b][w * 1024 + 512]);
    glds16(gB0 + k0, &Bs[b][w * 1024]);
    glds16(gB1 + k0, &Bs[b][w * 1024 + 512]);
  };
  f32x4 acc[4][4] = {};
  issue(0);
  issue(1);
  for (int t = 0; t < nt; t++){
    if (t < nt - 1) asm volatile("s_waitcnt vmcnt(4)\ns_barrier" ::: "memory");
    else            asm volatile("s_waitcnt vmcnt(0)\ns_barrier" ::: "memory");
    if (t + 2 < nt) issue(t + 2);
    int b = t - (t / 3) * 3;
    short8 a[4], bb[4];
    #pragma unroll
    for (int i = 0; i < 4; i++){
      int R = wr + i * 16 + lr;
      int pq = (l >> 4) ^ ((R >> 1) & 3);
      a[i] = *(short8*)&As[b][R * 32 + pq * 8];
    }
    #pragma unroll
    for (int j = 0; j < 4; j++){
      int R = wc + j * 16 + lr;
      int pq = (l >> 4) ^ ((R >> 1) & 3);
      bb[j] = *(short8*)&Bs[b][R * 32 + pq * 8];
    }
    #pragma unroll
    for (int i = 0; i < 4; i++)
      #pragma unroll
      for (int j = 0; j < 4; j++)
        acc[i][j] = __builtin_amdgcn_mfma_f32_16x16x32_bf16(a[i], bb[j], acc[i][j], 0, 0, 0);
  }
  const int orow = (l >> 4) * 4, ocol = l & 15;
  #pragma unroll
  for (int i = 0; i < 4; i++){
    #pragma unroll
    for (int j = 0; j < 4; j++){
      int gcol = bn + wc + j * 16 + ocol;
      float bv = bias ? bias[gcol] : 0.f;
      #pragma unroll
      for (int rg = 0; rg < 4; rg++){
        int grow = bm + wr + i * 16 + orow + rg;
        if (grow < M) stor(&C[(size_t)grow * ldc + gcol], acc[i][j][rg] + bv);
      }
    }
  }
}

// ---------------- pointer bundle for both layers ----------------
struct LPtrs {
  const float *gw[2], *al[2], *ar[2];
  const float *wqw[2], *wqb[2], *wkw[2], *wvw[2], *wvb[2];
  const float *ipw[2], *ipb[2], *opw[2], *opb[2];
  bf16* bigBT[2];
  float *ipwQT[2], *wkwT[2], *opwT[2], *wvwT[2];
  float *Wq[2], *B2[2], *M1[2], *bq[2];
  bf16* WvT[2];
  float *bv[2], *biasc[2];
  int* cnt;
};

// ---------------- fat prep: transGW | galr | wprep | zeroQK | zeroPad | zeroCnt, z = layer ----------------
#define PT0 1536
#define PT1 4608
#define PT2 4864
#define PT3 5248
#define PT4 5392
#define PT5 5524
__global__ __launch_bounds__(256)
void k_prep_all(LPtrs P){
  const int lay = blockIdx.z;
  const int b = blockIdx.x, tid = threadIdx.x;
  bf16* bigBT = P.bigBT[lay];
  if (b < PT0){
    __shared__ float t[32][33];
    int rel = b / 384, rem = b % 384;
    int n0 = (rem % 32) * 32, k0 = (rem / 32) * 32;
    const float* B = P.gw[lay] + (size_t)rel * 384 * 1024;
    bf16* BT = bigBT + (size_t)rel * 1024 * 384;
    int tx = tid & 31, ty = tid >> 5;
    for (int i = ty; i < 32; i += 8)
      t[i][tx] = B[(size_t)(k0 + i) * 1024 + n0 + tx];
    __syncthreads();
    for (int i = ty; i < 32; i += 8)
      BT[(size_t)(n0 + i) * 384 + k0 + tx] = __float2bfloat16(t[tx][i]);
  } else if (b < PT1){
    int bb = b - PT0;
    int kblk = bb % 96, r = bb / 96;
    int k = kblk * 4 + (tid >> 6), lane = tid & 63;
    int rr = r & 15, t = rr >> 2, h = rr & 3;
    const float* wsrc = ((r < 16) ? P.al[lay] : P.ar[lay]) + t * 1024 + h * 256;
    const float* gp = P.gw[lay] + (size_t)t * 384 * 1024 + (size_t)k * 1024 + h * 256;
    float v = 0.f;
    #pragma unroll
    for (int i = 0; i < 4; i++){
      int o = lane + i * 64;
      v += gp[o] * wsrc[o];
    }
    #pragma unroll
    for (int off = 32; off; off >>= 1) v += __shfl_down(v, off);
    if (lane == 0) bigBT[(size_t)(4352 + r) * 384 + k] = __float2bfloat16(v);
  } else if (b < PT2){
    __shared__ float t[32][33];
    int bb = b - PT1;
    int mat = bb >> 6, rem = bb & 63;
    int c0 = (rem & 7) * 32, r0 = (rem >> 3) * 32;
    const float* S; float* D;
    switch (mat){
      case 0: S = P.ipw[lay]; D = P.ipwQT[lay]; break;
      case 1: S = P.wkw[lay]; D = P.wkwT[lay]; break;
      case 2: S = P.opw[lay]; D = P.opwT[lay]; break;
      default: S = P.wvw[lay]; D = P.wvwT[lay]; break;
    }
    int tx = tid & 31, ty = tid >> 5;
    for (int i = ty; i < 32; i += 8)
      t[i][tx] = S[(size_t)(r0 + i) * 256 + c0 + tx];
    __syncthreads();
    for (int i = ty; i < 32; i += 8)
      D[(size_t)(c0 + i) * 256 + r0 + tx] = t[tx][i];
  } else if (b < PT3){
    int idx = (b - PT2) * 256 + tid;
    bigBT[(size_t)(4096 + idx / 384) * 384 + idx % 384] = __float2bfloat16(0.f);
  } else if (b < PT4){
    int idx = (b - PT3) * 256 + tid;
    bigBT[(size_t)(4384 + idx / 384) * 384 + idx % 384] = __float2bfloat16(0.f);
  } else if (lay == 0){
    int idx = (b - PT4) * 256 + tid;
    if (idx < 4 * KN) P.cnt[idx] = 0;
  }
}

// ---------------- F1 (z = layer) ----------------
__global__ __launch_bounds__(256)
void k_fold1(LPtrs P){
  const int lay = blockIdx.z;
  int b = blockIdx.x, tid = threadIdx.x;
  if (b < 128){
    int c = b; float s = 0.f;
    for (int e = 0; e < 256; e++) s += P.wqw[lay][c * 256 + e] * P.ipwQT[lay][e * 256 + tid];
    P.Wq[lay][c * 256 + tid] = s;
  } else if (b < 384){
    int j = b - 128; float s = 0.f;
    for (int e = 0; e < 256; e++) s += P.wkwT[lay][e * 256 + tid] * P.ipw[lay][(256 + j) * 256 + e];
    P.B2[lay][j * 256 + tid] = s;
  } else if (b < 640){
    int e = b - 384; float s = 0.f;
    for (int f = 0; f < 256; f++) s += P.ipw[lay][(512 + f) * 256 + e] * P.opwT[lay][f * 256 + tid];
    P.M1[lay][e * 256 + tid] = s;
  } else {
    float s = 0.f;
    for (int e = 0; e < 256; e++) s += P.wqb[lay][e] * P.ipwQT[lay][e * 256 + tid];
    P.bq[lay][tid] = s + P.ipb[lay][tid];
  }
}

// ---------------- F2 (z = layer) ----------------
__global__ __launch_bounds__(256)
void k_fold2(LPtrs P){
  const int lay = blockIdx.z;
  int b = blockIdx.x, tid = threadIdx.x;
  if (b < 256){
    __shared__ float wqr[256];
    wqr[tid] = P.Wq[lay][b * 256 + tid];
    __syncthreads();
    float s = 0.f;
    for (int j = 0; j < 256; j++) s += wqr[j] * P.B2[lay][j * 256 + tid];
    P.bigBT[lay][(size_t)(4096 + tid) * 384 + 256 + b] = __float2bfloat16(s);
  } else if (b < 512){
    int j = b - 256; float s = 0.f;
    for (int e = 0; e < 256; e++) s += P.wvwT[lay][e * 256 + tid] * P.M1[lay][e * 256 + j];
    P.WvT[lay][j * 256 + tid] = __float2bfloat16(s);
  } else {
    float b2 = 0.f;
    for (int j = 0; j < 256; j++) b2 += P.bq[lay][j] * P.B2[lay][j * 256 + tid];
    float s = 0.f;
    for (int e = 0; e < 256; e++) s += P.wvb[lay][e] * P.M1[lay][e * 256 + tid];
    for (int f = 0; f < 256; f++) s += P.ipb[lay][512 + f] * P.opwT[lay][f * 256 + tid];
    P.bv[lay][tid] = s + P.opb[lay][tid];
    for (int i = tid; i < NBIG; i += 256)
      P.biasc[lay][i] = (i - 4096 == tid) ? b2 : 0.f;
  }
}

// ---------------- pre-phase ----------------
__global__ __launch_bounds__(384)
void k_pre(const float* __restrict__ cf, const float* __restrict__ cfw, const float* __restrict__ cfb,
           const float* __restrict__ htw, const float* __restrict__ htb,
           float* __restrict__ cfvec, float* __restrict__ duc)
{
  int c = blockIdx.x;
  int col = threadIdx.x;
  __shared__ float row[512];
  for (int i = col; i < 512; i += 384) row[i] = cf[c * 512 + i];
  __syncthreads();
  if (col < 128){
    float acc = cfb[col];
    for (int k = 0; k < 512; k++) acc += row[k] * cfw[k * 128 + col];
    cfvec[c * 128 + col] = acc;
  } else {
    int j = col - 128;
    float acc = htb[j];
    for (int k = 0; k < 512; k++) acc += row[k] * htw[k * 256 + j];
    duc[c * 256 + j] = acc;
  }
}
__global__ void k_mean(const float* cv, float* m){
  int o = threadIdx.x;
  float s = 0.f;
  for (int c = 0; c < 64; c++) s += cv[c * 128 + o];
  m[o] = s * (1.f / 64.f);
}
// cfin cols 256..383 of b_inf for all rows (feat cols 0..255 for n<8192 are dead: L1 uses T12)
__global__ void k_cfincol(const float* __restrict__ cv, const float* __restrict__ cm,
                          bf16* __restrict__ inf){
  int n = blockIdx.x, oo = threadIdx.x; // 128
  float v;
  if (n < 8192)      v = cv[(n >> 7) * 128 + oo];
  else if (n < 8256) v = cv[(n - 8192) * 128 + oo];
  else               v = cm[oo];
  inf[(size_t)n * 384 + 256 + oo] = __float2bfloat16(v);
}
// strip rows 8192..8383: feat cols 0..255 (duc / x)
__global__ void k_infstrip(const float* __restrict__ x, const float* __restrict__ duc,
                           bf16* __restrict__ inf){
  int n = 8192 + blockIdx.x, o = threadIdx.x; // 256
  float v = (n < 8256) ? duc[(n - 8192) * 256 + o] : x[(n - 8256) * 256 + o];
  inf[(size_t)n * 384 + o] = __float2bfloat16(v);
}
// A12[256][384]: rows 0..127 = [x_i | 0]; rows 128..191 = [0 | cv_j]; rows 192..255 = 0
__global__ __launch_bounds__(384)
void k_smallA(const float* __restrict__ x, const float* __restrict__ cv,
              bf16* __restrict__ A12){
  int r = blockIdx.x, c = threadIdx.x;
  float v = 0.f;
  if (r < 128){
    if (c < 256) v = x[r * 256 + c];
  } else if (r < 192){
    if (c >= 256) v = cv[(r - 128) * 128 + (c - 256)];
  }
  A12[(size_t)r * 384 + c] = __float2bfloat16(v);
}
// expand FEAT cols only (0..4095) for rows 0..8191: big = T1 + T2 (biasc is 0 there)
__global__ __launch_bounds__(256)
void k_expandF(const bf16* __restrict__ T12, bf16* __restrict__ big){
  int n = blockIdx.x;
  const bf16* t1 = T12 + (size_t)(n & 127) * NBIG;
  const bf16* t2 = T12 + (size_t)(128 + (n >> 7)) * NBIG;
  bf16* out = big + (size_t)n * NBIG;
  #pragma unroll
  for (int it = 0; it < 2; it++){
    int c = threadIdx.x * 8 + it * 2048;
    short8 u = *(const short8*)&t1[c];
    short8 v = *(const short8*)&t2[c];
    #pragma unroll
    for (int i = 0; i < 8; i++)
      out[c + i] = __float2bfloat16(b2f(u[i]) + b2f(v[i]));
  }
}
__global__ void k_countB(const int* __restrict__ edges, int* __restrict__ cnt){
  int i = blockIdx.x * blockDim.x + threadIdx.x;
  if (i < 4 * KE){
    int t = i / KE, idx = i - t * KE;
    int d = edges[t * 2 * KE + KE + idx];
    atomicAdd(&cnt[t * KN + d], 1);
  }
}
__global__ void k_fillB(const int* __restrict__ edges, int* __restrict__ cur, int* __restrict__ csrc){
  int i = blockIdx.x * blockDim.x + threadIdx.x;
  if (i < 4 * KE){
    int t = i / KE, idx = i - t * KE;
    int s = edges[t * 2 * KE + idx];
    int d = edges[t * 2 * KE + KE + idx];
    int p = atomicAdd(&cur[t * KN + d], 1);
    csrc[p] = s;
  }
}
__global__ void k_scan(const int* __restrict__ cnt, int* __restrict__ ptr,
                       int* __restrict__ cur, int n){
  __shared__ int part[1024];
  int tid = threadIdx.x;
  const int CH = (n + 1023) >> 10;
  int base = tid * CH;
  int s = 0;
  for (int i = 0; i < CH; i++){ int idx = base + i; if (idx < n) s += cnt[idx]; }
  part[tid] = s; __syncthreads();
  for (int off = 1; off < 1024; off <<= 1){
    int v = (tid >= off) ? part[tid - off] : 0;
    __syncthreads();
    part[tid] += v;
    __syncthreads();
  }
  int run = part[tid] - s;
  for (int i = 0; i < CH; i++){
    int idx = base + i;
    if (idx < n){ ptr[idx] = run; cur[idx] = run; run += cnt[idx]; }
  }
  if (tid == 1023) ptr[n] = part[1023];
}

// ------------- fused GAT agg + attention: wave = relation; LR: elr/qk composed, feat from big -------------
template<int LR>
__global__ __launch_bounds__(256)
void k_aggattn(const int* __restrict__ ptr, const int* __restrict__ csrc,
               const bf16* __restrict__ big, const bf16* __restrict__ T12,
               const float* __restrict__ biasc, const float* __restrict__ gb,
               bf16* __restrict__ rbar)
{
  const int n = blockIdx.x, tid = threadIdx.x;
  const int w = tid >> 6, lane = tid & 63;
  const int t = w;
  const int head = lane >> 4;
  __shared__ float s_rst[16][260];
  __shared__ float s_sc[16];
  __shared__ float sa4[4][64][4];
  __shared__ int ssrcW[4][64];
  const int beg = ptr[t * KN + n], deg = ptr[t * KN + n + 1] - beg;
  auto elr4 = [&](int node, int base, float* out){
    if (LR && node < 8192){
      short4v u = *(const short4v*)&T12[(size_t)(node & 127) * NBIG + base + t * 4];
      short4v v = *(const short4v*)&T12[(size_t)(128 + (node >> 7)) * NBIG + base + t * 4];
      #pragma unroll
      for (int h = 0; h < 4; h++) out[h] = b2f(u[h]) + b2f(v[h]);
    } else {
      short4v u = *(const short4v*)&big[(size_t)node * NBIG + base + t * 4];
      #pragma unroll
      for (int h = 0; h < 4; h++) out[h] = b2f(u[h]);
    }
  };
  float ern[4];
  elr4(n, 4368, ern);
  float sums[4] = {0.f, 0.f, 0.f, 0.f};
  for (int j = lane; j < deg; j += 64){
    int s = csrc[beg + j];
    float el4[4];
    elr4(s, 4352, el4);
    #pragma unroll
    for (int h = 0; h < 4; h++){
      float e = el4[h] + ern[h];
      e = e > 0.f ? e : 0.2f * e;
      sums[h] += __expf(e);
    }
  }
  #pragma unroll
  for (int off = 32; off; off >>= 1){
    #pragma unroll
    for (int h = 0; h < 4; h++) sums[h] += __shfl_xor(sums[h], off);
  }
  float sinv[4];
  #pragma unroll
  for (int h = 0; h < 4; h++) sinv[h] = 1.f / fmaxf(sums[h], 1e-9f);
  float acc[16];
  #pragma unroll
  for (int i = 0; i < 16; i++) acc[i] = 0.f;
  const size_t cbase = (size_t)t * 1024 + lane * 16;
  for (int c0 = 0; c0 < deg; c0 += 64){
    int cn = min(64, deg - c0);
    if (lane < cn){
      int s = csrc[beg + c0 + lane];
      ssrcW[t][lane] = s;
      float el4[4];
      elr4(s, 4352, el4);
      #pragma unroll
      for (int h = 0; h < 4; h++){
        float e = el4[h] + ern[h];
        e = e > 0.f ? e : 0.2f * e;
        sa4[t][lane][h] = __expf(e) * sinv[h];
      }
    }
    int j = 0;
    for (; j + 3 < cn; j += 4){
      int s0 = ssrcW[t][j],     s1 = ssrcW[t][j + 1];
      int s2 = ssrcW[t][j + 2], s3 = ssrcW[t][j + 3];
      float w0 = sa4[t][j][head],     w1 = sa4[t][j + 1][head];
      float w2 = sa4[t][j + 2][head], w3 = sa4[t][j + 3][head];
      const bf16* f0 = &big[(size_t)s0 * NBIG + cbase];
      const bf16* f1 = &big[(size_t)s1 * NBIG + cbase];
      const bf16* f2 = &big[(size_t)s2 * NBIG + cbase];
      const bf16* f3 = &big[(size_t)s3 * NBIG + cbase];
      short8 a0 = *(const short8*)f0, b0 = *(const short8*)(f0 + 8);
      short8 a1 = *(const short8*)f1, b1 = *(const short8*)(f1 + 8);
      short8 a2 = *(const short8*)f2, b2 = *(const short8*)(f2 + 8);
      short8 a3 = *(const short8*)f3, b3 = *(const short8*)(f3 + 8);
      #pragma unroll
      for (int i = 0; i < 8; i++)
        acc[i] += w0 * b2f(a0[i]) + w1 * b2f(a1[i]) + w2 * b2f(a2[i]) + w3 * b2f(a3[i]);
      #pragma unroll
      for (int i = 0; i < 8; i++)
        acc[8 + i] += w0 * b2f(b0[i]) + w1 * b2f(b1[i]) + w2 * b2f(b2[i]) + w3 * b2f(b3[i]);
    }
    for (; j < cn; j++){
      int s = ssrcW[t][j];
      float wj = sa4[t][j][head];
      const bf16* fp = &big[(size_t)s * NBIG + cbase];
      short8 v0 = *(const short8*)fp;
      short8 v1 = *(const short8*)(fp + 8);
      #pragma unroll
      for (int i = 0; i < 8; i++) acc[i] += wj * b2f(v0[i]);
      #pragma unroll
      for (int i = 0; i < 8; i++) acc[8 + i] += wj * b2f(v1[i]);
    }
  }
  {
    const float* gbp = gb + t * 1024 + lane * 16;
    float* rp = &s_rst[t * 4 + head][(lane & 15) * 16];
    #pragma unroll
    for (int i = 0; i < 16; i++) rp[i] = acc[i] + gbp[i];
  }
  __syncthreads();
  #pragma unroll
  for (int si = 0; si < 4; si++){
    int s = w * 4 + si;
    float v = 0.f;
    #pragma unroll
    for (int i = 0; i < 4; i++){
      int o = lane + i * 64;
      float qo;
      if (LR && n < 8192)
        qo = b2f(T12[(size_t)(n & 127) * NBIG + 4096 + o]) +
             b2f(T12[(size_t)(128 + (n >> 7)) * NBIG + 4096 + o]) + biasc[4096 + o];
      else
        qo = toF(big[(size_t)n * NBIG + 4096 + o]);
      v += s_rst[s][o] * qo;
    }
    #pragma unroll
    for (int off = 32; off; off >>= 1) v += __shfl_down(v, off);
    if (lane == 0) s_sc[s] = v * 0.0625f;
  }
  __syncthreads();
  float sc[16]; float m = -1e30f;
  #pragma unroll
  for (int s = 0; s < 16; s++){ sc[s] = s_sc[s]; m = fmaxf(m, sc[s]); }
  float sum = 0.f;
  #pragma unroll
  for (int s = 0; s < 16; s++){ sc[s] = __expf(sc[s] - m); sum += sc[s]; }
  float inv = 1.f / sum;
  float r = 0.f;
  #pragma unroll
  for (int s = 0; s < 16; s++) r += sc[s] * s_rst[s][tid];
  rbar[(size_t)n * 256 + tid] = __float2bfloat16(r * inv);
}

extern "C" void kernel_launch(void* const* d_in, const int* in_sizes, int n_in,
                              void* d_out, int out_size, void* d_ws, size_t ws_size,
                              hipStream_t stream)
{
  const float* x   = (const float*)d_in[0];
  const float* cf  = (const float*)d_in[1];
  const float* cfw = (const float*)d_in[2];
  const float* cfb = (const float*)d_in[3];
  const float* htw = (const float*)d_in[4];
  const float* htb = (const float*)d_in[5];
  LPtrs P;
  const float* gbp[2];
  for (int l = 0; l < 2; l++){
    int b = 6 + l * 14;
    P.gw[l]  = (const float*)d_in[b + 0];
    P.al[l]  = (const float*)d_in[b + 1];
    P.ar[l]  = (const float*)d_in[b + 2];
    gbp[l]   = (const float*)d_in[b + 3];
    P.wqw[l] = (const float*)d_in[b + 4];
    P.wqb[l] = (const float*)d_in[b + 5];
    P.wkw[l] = (const float*)d_in[b + 6];
    P.wvw[l] = (const float*)d_in[b + 8];
    P.wvb[l] = (const float*)d_in[b + 9];
    P.ipw[l] = (const float*)d_in[b + 10];
    P.ipb[l] = (const float*)d_in[b + 11];
    P.opw[l] = (const float*)d_in[b + 12];
    P.opb[l] = (const float*)d_in[b + 13];
  }
  const int* edges = (const int*)d_in[34];

  // -------- workspace layout --------
  char* w = (char*)d_ws;
  size_t off = 0;
  auto alc = [&](size_t bytes) -> void* {
    off = (off + 255) & ~(size_t)255;
    void* p = w + off; off += bytes; return p;
  };
  float* f_cfvec = (float*)alc(64 * 128 * 4);
  float* f_cfmean= (float*)alc(128 * 4);
  float* f_duc   = (float*)alc(64 * 256 * 4);
  bf16*  b_inf   = (bf16*) alc((size_t)KNPAD * 384 * 2);
  bf16*  b_big   = (bf16*) alc((size_t)KN * NBIG * 2);
  bf16*  b_rbar  = (bf16*) alc((size_t)KNPAD * 256 * 2);
  bf16*  b_A12   = (bf16*) alc((size_t)256 * 384 * 2);
  bf16*  b_T12   = (bf16*) alc((size_t)192 * NBIG * 2);
  for (int l = 0; l < 2; l++){
    P.bigBT[l] = (bf16*) alc((size_t)NBIG * 384 * 2);
    P.biasc[l] = (float*)alc((size_t)NBIG * 4);
    P.ipwQT[l] = (float*)alc(256 * 256 * 4);
    P.wkwT[l]  = (float*)alc(256 * 256 * 4);
    P.opwT[l]  = (float*)alc(256 * 256 * 4);
    P.wvwT[l]  = (float*)alc(256 * 256 * 4);
    P.Wq[l]    = (float*)alc(128 * 256 * 4);
    P.B2[l]    = (float*)alc(256 * 256 * 4);
    P.M1[l]    = (float*)alc(256 * 256 * 4);
    P.bq[l]    = (float*)alc(256 * 4);
    P.bv[l]    = (float*)alc(256 * 4);
    P.WvT[l]   = (bf16*) alc(256 * 256 * 2);
  }
  int* i_ptr = (int*)alc((size_t)(4 * KN + 1) * 4);
  int* i_src = (int*)alc((size_t)4 * KE * 4);
  int* i_cnt = (int*)alc((size_t)4 * KN * 4);
  int* i_cur = (int*)alc((size_t)4 * KN * 4);
  P.cnt = i_cnt;
  if (off > ws_size) return;

  // -------- pre-phase + prep (both layers) --------
  k_pre<<<64, 384, 0, stream>>>(cf, cfw, cfb, htw, htb, f_cfvec, f_duc);
  k_mean<<<1, 128, 0, stream>>>(f_cfvec, f_cfmean);
  k_cfincol<<<KN, 128, 0, stream>>>(f_cfvec, f_cfmean, b_inf);
  k_infstrip<<<192, 256, 0, stream>>>(x, f_duc, b_inf);
  k_smallA<<<256, 384, 0, stream>>>(x, f_cfvec, b_A12);
  k_prep_all<<<dim3(PT5, 1, 2), 256, 0, stream>>>(P);
  k_fold1<<<dim3(641, 1, 2), 256, 0, stream>>>(P);
  k_fold2<<<dim3(513, 1, 2), 256, 0, stream>>>(P);

  // -------- batched CSR --------
  k_countB<<<(4 * KE + 255) / 256, 256, 0, stream>>>(edges, i_cnt);
  k_scan<<<1, 1024, 0, stream>>>(i_cnt, i_ptr, i_cur, 4 * KN);
  k_fillB<<<(4 * KE + 255) / 256, 256, 0, stream>>>(edges, i_cur, i_src);

  // -------- layer 1: low-rank; feat expanded, elr/qk composed --------
  gemm_mfma_bt<bf16><<<(NBIG / 128) * 2, 256, 0, stream>>>(
      b_A12, P.bigBT[0], nullptr, b_T12, 192, NBIG, 384, NBIG, NBIG / 128);
  gemm_mfma_bt<bf16><<<(NBIG / 128) * 2, 256, 0, stream>>>(
      b_inf + (size_t)8192 * 384, P.bigBT[0], P.biasc[0],
      b_big + (size_t)8192 * NBIG, 192, NBIG, 384, NBIG, NBIG / 128);
  k_expandF<<<8192, 256, 0, stream>>>(b_T12, b_big);
  k_aggattn<1><<<KN, 256, 0, stream>>>(i_ptr, i_src, b_big, b_T12, P.biasc[0], gbp[0], b_rbar);
  gemm_mfma_bt<bf16><<<2 * 66, 256, 0, stream>>>(
      b_rbar, P.WvT[0], P.bv[0], b_inf, KN, 256, 256, 384, 2);

  // -------- layer 2: full megaGEMM --------
  gemm_mfma_bt<bf16><<<(NBIG / 128) * 66, 256, 0, stream>>>(
      b_inf, P.bigBT[1], P.biasc[1], b_big, KN, NBIG, 384, NBIG, NBIG / 128);
  k_aggattn<0><<<KN, 256, 0, stream>>>(i_ptr, i_src, b_big, b_T12, P.biasc[1], gbp[1], b_rbar);
  gemm_mfma_bt<float><<<2 * 66, 256, 0, stream>>>(
      b_rbar, P.WvT[1], P.bv[1], (float*)d_out, KN, 256, 256, 256, 2);
}

// Round 22
// 491.045 us; speedup vs baseline: 1.0543x; 1.0543x over previous
//
#include <hip/hip_runtime.h>
#include <hip/hip_bf16.h>

typedef __hip_bfloat16 bf16;
typedef __attribute__((ext_vector_type(8))) short short8;
typedef __attribute__((ext_vector_type(4))) short short4v;
typedef __attribute__((ext_vector_type(4))) float f32x4;

#define KN 8384
#define KNPAD 8448
#define KE 50000
#define NBIG 4480    /* 4096 feat + 256 qk + 128 elr(pad) = 35*128 */

__device__ __forceinline__ float toF(float v){ return v; }
__device__ __forceinline__ float toF(bf16 v){ return __bfloat162float(v); }
__device__ __forceinline__ float b2f(short u){ return __uint_as_float(((unsigned int)(unsigned short)u) << 16); }
__device__ __forceinline__ void stor(float* p, float v){ *p = v; }
__device__ __forceinline__ void stor(bf16* p, float v){ *p = __float2bfloat16(v); }

__device__ __forceinline__ void glds16(const bf16* g, bf16* l){
  __builtin_amdgcn_global_load_lds(
      (const __attribute__((address_space(1))) unsigned int*)(g),
      (__attribute__((address_space(3))) unsigned int*)(l), 16, 0, 0);
}

// ---------------- MFMA GEMM: 3-buf glds pipeline, vmcnt(4), XCD-chunked swizzle ----------------
template<typename TC>
__global__ __launch_bounds__(256)
void gemm_mfma_bt(const bf16* __restrict__ A, const bf16* __restrict__ BT,
                  const float* __restrict__ bias, TC* __restrict__ C,
                  int M, int N, int K, int ldc, int nbx)
{
  __shared__ bf16 As[3][128 * 32];
  __shared__ bf16 Bs[3][128 * 32];
  const int nwg = gridDim.x;
  const int q = nwg >> 3, r = nwg & 7;
  const int xcd = blockIdx.x & 7, idx = blockIdx.x >> 3;
  const int sw = (xcd < r) ? xcd * (q + 1) + idx : r * (q + 1) + (xcd - r) * q + idx;
  const int bn = (sw % nbx) * 128, bm = (sw / nbx) * 128;
  const int tid = threadIdx.x;
  const int w = tid >> 6, l = tid & 63;
  const int wr = (w >> 1) * 64, wc = (w & 1) * 64;
  const int lr = l & 15;
  int rS[2], lqS[2];
  #pragma unroll
  for (int i = 0; i < 2; i++){
    rS[i] = w * 32 + i * 16 + (l >> 2);
    lqS[i] = (l & 3) ^ ((rS[i] >> 1) & 3);
  }
  const bf16* gA0 = A  + (size_t)(bm + rS[0]) * K + lqS[0] * 8;
  const bf16* gA1 = A  + (size_t)(bm + rS[1]) * K + lqS[1] * 8;
  const bf16* gB0 = BT + (size_t)(bn + rS[0]) * K + lqS[0] * 8;
  const bf16* gB1 = BT + (size_t)(bn + rS[1]) * K + lqS[1] * 8;
  const int nt = K >> 5;
  auto issue = [&](int t){
    int b = t - (t / 3) * 3;
    int k0 = t << 5;
    glds16(gA0 + k0, &As[b][w * 1024]);
    glds16(gA1 + k0, &As[b][w * 1024 + 512]);
    glds16(gB0 + k0, &Bs[b][w * 1024]);
    glds16(gB1 + k0, &Bs[b][w * 1024 + 512]);
  };
  f32x4 acc[4][4] = {};
  issue(0);
  issue(1);
  for (int t = 0; t < nt; t++){
    if (t < nt - 1) asm volatile("s_waitcnt vmcnt(4)\ns_barrier" ::: "memory");
    else            asm volatile("s_waitcnt vmcnt(0)\ns_barrier" ::: "memory");
    if (t + 2 < nt) issue(t + 2);
    int b = t - (t / 3) * 3;
    short8 a[4], bb[4];
    #pragma unroll
    for (int i = 0; i < 4; i++){
      int R = wr + i * 16 + lr;
      int pq = (l >> 4) ^ ((R >> 1) & 3);
      a[i] = *(short8*)&As[b][R * 32 + pq * 8];
    }
    #pragma unroll
    for (int j = 0; j < 4; j++){
      int R = wc + j * 16 + lr;
      int pq = (l >> 4) ^ ((R >> 1) & 3);
      bb[j] = *(short8*)&Bs[b][R * 32 + pq * 8];
    }
    #pragma unroll
    for (int i = 0; i < 4; i++)
      #pragma unroll
      for (int j = 0; j < 4; j++)
        acc[i][j] = __builtin_amdgcn_mfma_f32_16x16x32_bf16(a[i], bb[j], acc[i][j], 0, 0, 0);
  }
  const int orow = (l >> 4) * 4, ocol = l & 15;
  #pragma unroll
  for (int i = 0; i < 4; i++){
    #pragma unroll
    for (int j = 0; j < 4; j++){
      int gcol = bn + wc + j * 16 + ocol;
      float bv = bias ? bias[gcol] : 0.f;
      #pragma unroll
      for (int rg = 0; rg < 4; rg++){
        int grow = bm + wr + i * 16 + orow + rg;
        if (grow < M) stor(&C[(size_t)grow * ldc + gcol], acc[i][j][rg] + bv);
      }
    }
  }
}

// ---------------- pointer bundle for both layers ----------------
struct LPtrs {
  const float *gw[2], *al[2], *ar[2];
  const float *wqw[2], *wqb[2], *wkw[2], *wvw[2], *wvb[2];
  const float *ipw[2], *ipb[2], *opw[2], *opb[2];
  bf16* bigBT[2];
  float *ipwQT[2], *wkwT[2], *opwT[2], *wvwT[2];
  float *Wq[2], *B2[2], *M1[2], *bq[2];
  bf16* WvT[2];
  float *bv[2], *biasc[2];
  int* cnt;
};

// ---------------- fat prep: transGW | galr | wprep | zeroQK | zeroPad | zeroCnt, z = layer ----------------
#define PT0 1536
#define PT1 4608
#define PT2 4864
#define PT3 5248
#define PT4 5392
#define PT5 5524
__global__ __launch_bounds__(256)
void k_prep_all(LPtrs P){
  const int lay = blockIdx.z;
  const int b = blockIdx.x, tid = threadIdx.x;
  bf16* bigBT = P.bigBT[lay];
  if (b < PT0){
    __shared__ float t[32][33];
    int rel = b / 384, rem = b % 384;
    int n0 = (rem % 32) * 32, k0 = (rem / 32) * 32;
    const float* B = P.gw[lay] + (size_t)rel * 384 * 1024;
    bf16* BT = bigBT + (size_t)rel * 1024 * 384;
    int tx = tid & 31, ty = tid >> 5;
    for (int i = ty; i < 32; i += 8)
      t[i][tx] = B[(size_t)(k0 + i) * 1024 + n0 + tx];
    __syncthreads();
    for (int i = ty; i < 32; i += 8)
      BT[(size_t)(n0 + i) * 384 + k0 + tx] = __float2bfloat16(t[tx][i]);
  } else if (b < PT1){
    int bb = b - PT0;
    int kblk = bb % 96, r = bb / 96;
    int k = kblk * 4 + (tid >> 6), lane = tid & 63;
    int rr = r & 15, t = rr >> 2, h = rr & 3;
    const float* wsrc = ((r < 16) ? P.al[lay] : P.ar[lay]) + t * 1024 + h * 256;
    const float* gp = P.gw[lay] + (size_t)t * 384 * 1024 + (size_t)k * 1024 + h * 256;
    float v = 0.f;
    #pragma unroll
    for (int i = 0; i < 4; i++){
      int o = lane + i * 64;
      v += gp[o] * wsrc[o];
    }
    #pragma unroll
    for (int off = 32; off; off >>= 1) v += __shfl_down(v, off);
    if (lane == 0) bigBT[(size_t)(4352 + r) * 384 + k] = __float2bfloat16(v);
  } else if (b < PT2){
    __shared__ float t[32][33];
    int bb = b - PT1;
    int mat = bb >> 6, rem = bb & 63;
    int c0 = (rem & 7) * 32, r0 = (rem >> 3) * 32;
    const float* S; float* D;
    switch (mat){
      case 0: S = P.ipw[lay]; D = P.ipwQT[lay]; break;
      case 1: S = P.wkw[lay]; D = P.wkwT[lay]; break;
      case 2: S = P.opw[lay]; D = P.opwT[lay]; break;
      default: S = P.wvw[lay]; D = P.wvwT[lay]; break;
    }
    int tx = tid & 31, ty = tid >> 5;
    for (int i = ty; i < 32; i += 8)
      t[i][tx] = S[(size_t)(r0 + i) * 256 + c0 + tx];
    __syncthreads();
    for (int i = ty; i < 32; i += 8)
      D[(size_t)(c0 + i) * 256 + r0 + tx] = t[tx][i];
  } else if (b < PT3){
    int idx = (b - PT2) * 256 + tid;
    bigBT[(size_t)(4096 + idx / 384) * 384 + idx % 384] = __float2bfloat16(0.f);
  } else if (b < PT4){
    int idx = (b - PT3) * 256 + tid;
    bigBT[(size_t)(4384 + idx / 384) * 384 + idx % 384] = __float2bfloat16(0.f);
  } else if (lay == 0){
    int idx = (b - PT4) * 256 + tid;
    if (idx < 4 * KN) P.cnt[idx] = 0;
  }
}

// ---------------- F1 (z = layer) ----------------
__global__ __launch_bounds__(256)
void k_fold1(LPtrs P){
  const int lay = blockIdx.z;
  int b = blockIdx.x, tid = threadIdx.x;
  if (b < 128){
    int c = b; float s = 0.f;
    for (int e = 0; e < 256; e++) s += P.wqw[lay][c * 256 + e] * P.ipwQT[lay][e * 256 + tid];
    P.Wq[lay][c * 256 + tid] = s;
  } else if (b < 384){
    int j = b - 128; float s = 0.f;
    for (int e = 0; e < 256; e++) s += P.wkwT[lay][e * 256 + tid] * P.ipw[lay][(256 + j) * 256 + e];
    P.B2[lay][j * 256 + tid] = s;
  } else if (b < 640){
    int e = b - 384; float s = 0.f;
    for (int f = 0; f < 256; f++) s += P.ipw[lay][(512 + f) * 256 + e] * P.opwT[lay][f * 256 + tid];
    P.M1[lay][e * 256 + tid] = s;
  } else {
    float s = 0.f;
    for (int e = 0; e < 256; e++) s += P.wqb[lay][e] * P.ipwQT[lay][e * 256 + tid];
    P.bq[lay][tid] = s + P.ipb[lay][tid];
  }
}

// ---------------- F2 (z = layer) ----------------
__global__ __launch_bounds__(256)
void k_fold2(LPtrs P){
  const int lay = blockIdx.z;
  int b = blockIdx.x, tid = threadIdx.x;
  if (b < 256){
    __shared__ float wqr[256];
    wqr[tid] = P.Wq[lay][b * 256 + tid];
    __syncthreads();
    float s = 0.f;
    for (int j = 0; j < 256; j++) s += wqr[j] * P.B2[lay][j * 256 + tid];
    P.bigBT[lay][(size_t)(4096 + tid) * 384 + 256 + b] = __float2bfloat16(s);
  } else if (b < 512){
    int j = b - 256; float s = 0.f;
    for (int e = 0; e < 256; e++) s += P.wvwT[lay][e * 256 + tid] * P.M1[lay][e * 256 + j];
    P.WvT[lay][j * 256 + tid] = __float2bfloat16(s);
  } else {
    float b2 = 0.f;
    for (int j = 0; j < 256; j++) b2 += P.bq[lay][j] * P.B2[lay][j * 256 + tid];
    float s = 0.f;
    for (int e = 0; e < 256; e++) s += P.wvb[lay][e] * P.M1[lay][e * 256 + tid];
    for (int f = 0; f < 256; f++) s += P.ipb[lay][512 + f] * P.opwT[lay][f * 256 + tid];
    P.bv[lay][tid] = s + P.opb[lay][tid];
    for (int i = tid; i < NBIG; i += 256)
      P.biasc[lay][i] = (i - 4096 == tid) ? b2 : 0.f;
  }
}

// ---------------- pre-phase ----------------
__global__ __launch_bounds__(384)
void k_pre(const float* __restrict__ cf, const float* __restrict__ cfw, const float* __restrict__ cfb,
           const float* __restrict__ htw, const float* __restrict__ htb,
           float* __restrict__ cfvec, float* __restrict__ duc)
{
  int c = blockIdx.x;
  int col = threadIdx.x;
  __shared__ float row[512];
  for (int i = col; i < 512; i += 384) row[i] = cf[c * 512 + i];
  __syncthreads();
  if (col < 128){
    float acc = cfb[col];
    for (int k = 0; k < 512; k++) acc += row[k] * cfw[k * 128 + col];
    cfvec[c * 128 + col] = acc;
  } else {
    int j = col - 128;
    float acc = htb[j];
    for (int k = 0; k < 512; k++) acc += row[k] * htw[k * 256 + j];
    duc[c * 256 + j] = acc;
  }
}
__global__ void k_mean(const float* cv, float* m){
  int o = threadIdx.x;
  float s = 0.f;
  for (int c = 0; c < 64; c++) s += cv[c * 128 + o];
  m[o] = s * (1.f / 64.f);
}
// cfin cols 256..383 of b_inf for all rows (feat cols for n<8192 are dead in layer 1)
__global__ void k_cfincol(const float* __restrict__ cv, const float* __restrict__ cm,
                          bf16* __restrict__ inf){
  int n = blockIdx.x, oo = threadIdx.x; // 128
  float v;
  if (n < 8192)      v = cv[(n >> 7) * 128 + oo];
  else if (n < 8256) v = cv[(n - 8192) * 128 + oo];
  else               v = cm[oo];
  inf[(size_t)n * 384 + 256 + oo] = __float2bfloat16(v);
}
// strip rows 8192..8383: feat cols 0..255 (duc / x)
__global__ void k_infstrip(const float* __restrict__ x, const float* __restrict__ duc,
                           bf16* __restrict__ inf){
  int n = 8192 + blockIdx.x, o = threadIdx.x; // 256
  float v = (n < 8256) ? duc[(n - 8192) * 256 + o] : x[(n - 8256) * 256 + o];
  inf[(size_t)n * 384 + o] = __float2bfloat16(v);
}
// A12[256][384]: rows 0..127 = [x_i | 0]; rows 128..191 = [0 | cv_j]; rows 192..255 = 0
__global__ __launch_bounds__(384)
void k_smallA(const float* __restrict__ x, const float* __restrict__ cv,
              bf16* __restrict__ A12){
  int r = blockIdx.x, c = threadIdx.x;
  float v = 0.f;
  if (r < 128){
    if (c < 256) v = x[r * 256 + c];
  } else if (r < 192){
    if (c >= 256) v = cv[(r - 128) * 128 + (c - 256)];
  }
  A12[(size_t)r * 384 + c] = __float2bfloat16(v);
}
__global__ void k_countB(const int* __restrict__ edges, int* __restrict__ cnt){
  int i = blockIdx.x * blockDim.x + threadIdx.x;
  if (i < 4 * KE){
    int t = i / KE, idx = i - t * KE;
    int d = edges[t * 2 * KE + KE + idx];
    atomicAdd(&cnt[t * KN + d], 1);
  }
}
__global__ void k_fillB(const int* __restrict__ edges, int* __restrict__ cur, int* __restrict__ csrc){
  int i = blockIdx.x * blockDim.x + threadIdx.x;
  if (i < 4 * KE){
    int t = i / KE, idx = i - t * KE;
    int s = edges[t * 2 * KE + idx];
    int d = edges[t * 2 * KE + KE + idx];
    int p = atomicAdd(&cur[t * KN + d], 1);
    csrc[p] = s;
  }
}
__global__ void k_scan(const int* __restrict__ cnt, int* __restrict__ ptr,
                       int* __restrict__ cur, int n){
  __shared__ int part[1024];
  int tid = threadIdx.x;
  const int CH = (n + 1023) >> 10;
  int base = tid * CH;
  int s = 0;
  for (int i = 0; i < CH; i++){ int idx = base + i; if (idx < n) s += cnt[idx]; }
  part[tid] = s; __syncthreads();
  for (int off = 1; off < 1024; off <<= 1){
    int v = (tid >= off) ? part[tid - off] : 0;
    __syncthreads();
    part[tid] += v;
    __syncthreads();
  }
  int run = part[tid] - s;
  for (int i = 0; i < CH; i++){
    int idx = base + i;
    if (idx < n){ ptr[idx] = run; cur[idx] = run; run += cnt[idx]; }
  }
  if (tid == 1023) ptr[n] = part[1023];
}

// ------------- L1 aggattn: full low-rank composition (round-20 winner) -------------
__global__ __launch_bounds__(256)
void k_aggattn_lr(const int* __restrict__ ptr, const int* __restrict__ csrc,
                  const bf16* __restrict__ big, const bf16* __restrict__ T12,
                  const float* __restrict__ biasc, const float* __restrict__ gb,
                  bf16* __restrict__ rbar)
{
  const int n = blockIdx.x, tid = threadIdx.x;
  const int w = tid >> 6, lane = tid & 63;
  const int t = w;
  const int head = lane >> 4;
  __shared__ float s_rst[16][260];
  __shared__ float s_sc[16];
  __shared__ float sa4[4][64][4];
  __shared__ int ssrcW[4][64];
  const int beg = ptr[t * KN + n], deg = ptr[t * KN + n + 1] - beg;
  auto elr4 = [&](int node, int base, float* out){
    if (node < 8192){
      short4v u = *(const short4v*)&T12[(size_t)(node & 127) * NBIG + base + t * 4];
      short4v v = *(const short4v*)&T12[(size_t)(128 + (node >> 7)) * NBIG + base + t * 4];
      #pragma unroll
      for (int h = 0; h < 4; h++) out[h] = b2f(u[h]) + b2f(v[h]);
    } else {
      short4v u = *(const short4v*)&big[(size_t)node * NBIG + base + t * 4];
      #pragma unroll
      for (int h = 0; h < 4; h++) out[h] = b2f(u[h]);
    }
  };
  float ern[4];
  elr4(n, 4368, ern);
  float sums[4] = {0.f, 0.f, 0.f, 0.f};
  for (int j = lane; j < deg; j += 64){
    int s = csrc[beg + j];
    float el4[4];
    elr4(s, 4352, el4);
    #pragma unroll
    for (int h = 0; h < 4; h++){
      float e = el4[h] + ern[h];
      e = e > 0.f ? e : 0.2f * e;
      sums[h] += __expf(e);
    }
  }
  #pragma unroll
  for (int off = 32; off; off >>= 1){
    #pragma unroll
    for (int h = 0; h < 4; h++) sums[h] += __shfl_xor(sums[h], off);
  }
  float sinv[4];
  #pragma unroll
  for (int h = 0; h < 4; h++) sinv[h] = 1.f / fmaxf(sums[h], 1e-9f);
  float acc[16];
  #pragma unroll
  for (int i = 0; i < 16; i++) acc[i] = 0.f;
  const size_t cbase = (size_t)t * 1024 + lane * 16;
  for (int c0 = 0; c0 < deg; c0 += 64){
    int cn = min(64, deg - c0);
    if (lane < cn){
      int s = csrc[beg + c0 + lane];
      ssrcW[t][lane] = s;
      float el4[4];
      elr4(s, 4352, el4);
      #pragma unroll
      for (int h = 0; h < 4; h++){
        float e = el4[h] + ern[h];
        e = e > 0.f ? e : 0.2f * e;
        sa4[t][lane][h] = __expf(e) * sinv[h];
      }
    }
    for (int j = 0; j < cn; j++){
      int s = ssrcW[t][j];
      float wj = sa4[t][j][head];
      if (s < 8192){
        const bf16* p1 = &T12[(size_t)(s & 127) * NBIG + cbase];
        const bf16* p2 = &T12[(size_t)(128 + (s >> 7)) * NBIG + cbase];
        short8 u0 = *(const short8*)p1, u1 = *(const short8*)(p1 + 8);
        short8 v0 = *(const short8*)p2, v1 = *(const short8*)(p2 + 8);
        #pragma unroll
        for (int i = 0; i < 8; i++) acc[i] += wj * (b2f(u0[i]) + b2f(v0[i]));
        #pragma unroll
        for (int i = 0; i < 8; i++) acc[8 + i] += wj * (b2f(u1[i]) + b2f(v1[i]));
      } else {
        const bf16* fp = &big[(size_t)s * NBIG + cbase];
        short8 v0 = *(const short8*)fp, v1 = *(const short8*)(fp + 8);
        #pragma unroll
        for (int i = 0; i < 8; i++) acc[i] += wj * b2f(v0[i]);
        #pragma unroll
        for (int i = 0; i < 8; i++) acc[8 + i] += wj * b2f(v1[i]);
      }
    }
  }
  {
    const float* gbp = gb + t * 1024 + lane * 16;
    float* rp = &s_rst[t * 4 + head][(lane & 15) * 16];
    #pragma unroll
    for (int i = 0; i < 16; i++) rp[i] = acc[i] + gbp[i];
  }
  __syncthreads();
  #pragma unroll
  for (int si = 0; si < 4; si++){
    int s = w * 4 + si;
    float v = 0.f;
    #pragma unroll
    for (int i = 0; i < 4; i++){
      int o = lane + i * 64;
      float qo;
      if (n < 8192)
        qo = b2f(T12[(size_t)(n & 127) * NBIG + 4096 + o]) +
             b2f(T12[(size_t)(128 + (n >> 7)) * NBIG + 4096 + o]) + biasc[4096 + o];
      else
        qo = toF(big[(size_t)n * NBIG + 4096 + o]);
      v += s_rst[s][o] * qo;
    }
    #pragma unroll
    for (int off = 32; off; off >>= 1) v += __shfl_down(v, off);
    if (lane == 0) s_sc[s] = v * 0.0625f;
  }
  __syncthreads();
  float sc[16]; float m = -1e30f;
  #pragma unroll
  for (int s = 0; s < 16; s++){ sc[s] = s_sc[s]; m = fmaxf(m, sc[s]); }
  float sum = 0.f;
  #pragma unroll
  for (int s = 0; s < 16; s++){ sc[s] = __expf(sc[s] - m); sum += sc[s]; }
  float inv = 1.f / sum;
  float r = 0.f;
  #pragma unroll
  for (int s = 0; s < 16; s++) r += sc[s] * s_rst[s][tid];
  rbar[(size_t)n * 256 + tid] = __float2bfloat16(r * inv);
}

// ------------- L2 aggattn: plain materialized big (round-16 proven) -------------
__global__ __launch_bounds__(256)
void k_aggattn_pl(const int* __restrict__ ptr, const int* __restrict__ csrc,
                  const bf16* __restrict__ big, const float* __restrict__ gb,
                  bf16* __restrict__ rbar)
{
  const int n = blockIdx.x, tid = threadIdx.x;
  const int w = tid >> 6, lane = tid & 63;
  const int t = w;
  const int head = lane >> 4;
  __shared__ float s_rst[16][260];
  __shared__ float s_sc[16];
  __shared__ float sa4[4][64][4];
  __shared__ int ssrcW[4][64];
  const int beg = ptr[t * KN + n], deg = ptr[t * KN + n + 1] - beg;
  short4v e4 = *(const short4v*)&big[(size_t)n * NBIG + 4368 + t * 4];
  float ern[4] = {b2f(e4[0]), b2f(e4[1]), b2f(e4[2]), b2f(e4[3])};
  float sums[4] = {0.f, 0.f, 0.f, 0.f};
  for (int j = lane; j < deg; j += 64){
    int s = csrc[beg + j];
    short4v l4 = *(const short4v*)&big[(size_t)s * NBIG + 4352 + t * 4];
    #pragma unroll
    for (int h = 0; h < 4; h++){
      float e = b2f(l4[h]) + ern[h];
      e = e > 0.f ? e : 0.2f * e;
      sums[h] += __expf(e);
    }
  }
  #pragma unroll
  for (int off = 32; off; off >>= 1){
    #pragma unroll
    for (int h = 0; h < 4; h++) sums[h] += __shfl_xor(sums[h], off);
  }
  float sinv[4];
  #pragma unroll
  for (int h = 0; h < 4; h++) sinv[h] = 1.f / fmaxf(sums[h], 1e-9f);
  float acc[16];
  #pragma unroll
  for (int i = 0; i < 16; i++) acc[i] = 0.f;
  const size_t cbase = (size_t)t * 1024 + lane * 16;
  for (int c0 = 0; c0 < deg; c0 += 64){
    int cn = min(64, deg - c0);
    if (lane < cn){
      int s = csrc[beg + c0 + lane];
      ssrcW[t][lane] = s;
      short4v l4 = *(const short4v*)&big[(size_t)s * NBIG + 4352 + t * 4];
      #pragma unroll
      for (int h = 0; h < 4; h++){
        float e = b2f(l4[h]) + ern[h];
        e = e > 0.f ? e : 0.2f * e;
        sa4[t][lane][h] = __expf(e) * sinv[h];
      }
    }
    int j = 0;
    for (; j + 3 < cn; j += 4){
      int s0 = ssrcW[t][j],     s1 = ssrcW[t][j + 1];
      int s2 = ssrcW[t][j + 2], s3 = ssrcW[t][j + 3];
      float w0 = sa4[t][j][head],     w1 = sa4[t][j + 1][head];
      float w2 = sa4[t][j + 2][head], w3 = sa4[t][j + 3][head];
      const bf16* f0 = &big[(size_t)s0 * NBIG + cbase];
      const bf16* f1 = &big[(size_t)s1 * NBIG + cbase];
      const bf16* f2 = &big[(size_t)s2 * NBIG + cbase];
      const bf16* f3 = &big[(size_t)s3 * NBIG + cbase];
      short8 a0 = *(const short8*)f0, b0 = *(const short8*)(f0 + 8);
      short8 a1 = *(const short8*)f1, b1 = *(const short8*)(f1 + 8);
      short8 a2 = *(const short8*)f2, b2 = *(const short8*)(f2 + 8);
      short8 a3 = *(const short8*)f3, b3 = *(const short8*)(f3 + 8);
      #pragma unroll
      for (int i = 0; i < 8; i++)
        acc[i] += w0 * b2f(a0[i]) + w1 * b2f(a1[i]) + w2 * b2f(a2[i]) + w3 * b2f(a3[i]);
      #pragma unroll
      for (int i = 0; i < 8; i++)
        acc[8 + i] += w0 * b2f(b0[i]) + w1 * b2f(b1[i]) + w2 * b2f(b2[i]) + w3 * b2f(b3[i]);
    }
    for (; j < cn; j++){
      int s = ssrcW[t][j];
      float wj = sa4[t][j][head];
      const bf16* fp = &big[(size_t)s * NBIG + cbase];
      short8 v0 = *(const short8*)fp;
      short8 v1 = *(const short8*)(fp + 8);
      #pragma unroll
      for (int i = 0; i < 8; i++) acc[i] += wj * b2f(v0[i]);
      #pragma unroll
      for (int i = 0; i < 8; i++) acc[8 + i] += wj * b2f(v1[i]);
    }
  }
  {
    const float* gbp = gb + t * 1024 + lane * 16;
    float* rp = &s_rst[t * 4 + head][(lane & 15) * 16];
    #pragma unroll
    for (int i = 0; i < 16; i++) rp[i] = acc[i] + gbp[i];
  }
  __syncthreads();
  const bf16* qq = big + (size_t)n * NBIG + 4096;
  #pragma unroll
  for (int si = 0; si < 4; si++){
    int s = w * 4 + si;
    float v = 0.f;
    #pragma unroll
    for (int i = 0; i < 4; i++){
      int o = lane + i * 64;
      v += s_rst[s][o] * toF(qq[o]);
    }
    #pragma unroll
    for (int off = 32; off; off >>= 1) v += __shfl_down(v, off);
    if (lane == 0) s_sc[s] = v * 0.0625f;
  }
  __syncthreads();
  float sc[16]; float m = -1e30f;
  #pragma unroll
  for (int s = 0; s < 16; s++){ sc[s] = s_sc[s]; m = fmaxf(m, sc[s]); }
  float sum = 0.f;
  #pragma unroll
  for (int s = 0; s < 16; s++){ sc[s] = __expf(sc[s] - m); sum += sc[s]; }
  float inv = 1.f / sum;
  float r = 0.f;
  #pragma unroll
  for (int s = 0; s < 16; s++) r += sc[s] * s_rst[s][tid];
  rbar[(size_t)n * 256 + tid] = __float2bfloat16(r * inv);
}

extern "C" void kernel_launch(void* const* d_in, const int* in_sizes, int n_in,
                              void* d_out, int out_size, void* d_ws, size_t ws_size,
                              hipStream_t stream)
{
  const float* x   = (const float*)d_in[0];
  const float* cf  = (const float*)d_in[1];
  const float* cfw = (const float*)d_in[2];
  const float* cfb = (const float*)d_in[3];
  const float* htw = (const float*)d_in[4];
  const float* htb = (const float*)d_in[5];
  LPtrs P;
  const float* gbp[2];
  for (int l = 0; l < 2; l++){
    int b = 6 + l * 14;
    P.gw[l]  = (const float*)d_in[b + 0];
    P.al[l]  = (const float*)d_in[b + 1];
    P.ar[l]  = (const float*)d_in[b + 2];
    gbp[l]   = (const float*)d_in[b + 3];
    P.wqw[l] = (const float*)d_in[b + 4];
    P.wqb[l] = (const float*)d_in[b + 5];
    P.wkw[l] = (const float*)d_in[b + 6];
    P.wvw[l] = (const float*)d_in[b + 8];
    P.wvb[l] = (const float*)d_in[b + 9];
    P.ipw[l] = (const float*)d_in[b + 10];
    P.ipb[l] = (const float*)d_in[b + 11];
    P.opw[l] = (const float*)d_in[b + 12];
    P.opb[l] = (const float*)d_in[b + 13];
  }
  const int* edges = (const int*)d_in[34];

  // -------- workspace layout --------
  char* w = (char*)d_ws;
  size_t off = 0;
  auto alc = [&](size_t bytes) -> void* {
    off = (off + 255) & ~(size_t)255;
    void* p = w + off; off += bytes; return p;
  };
  float* f_cfvec = (float*)alc(64 * 128 * 4);
  float* f_cfmean= (float*)alc(128 * 4);
  float* f_duc   = (float*)alc(64 * 256 * 4);
  bf16*  b_inf   = (bf16*) alc((size_t)KNPAD * 384 * 2);
  bf16*  b_big   = (bf16*) alc((size_t)KN * NBIG * 2);
  bf16*  b_rbar  = (bf16*) alc((size_t)KNPAD * 256 * 2);
  bf16*  b_A12   = (bf16*) alc((size_t)256 * 384 * 2);
  bf16*  b_T12   = (bf16*) alc((size_t)192 * NBIG * 2);
  for (int l = 0; l < 2; l++){
    P.bigBT[l] = (bf16*) alc((size_t)NBIG * 384 * 2);
    P.biasc[l] = (float*)alc((size_t)NBIG * 4);
    P.ipwQT[l] = (float*)alc(256 * 256 * 4);
    P.wkwT[l]  = (float*)alc(256 * 256 * 4);
    P.opwT[l]  = (float*)alc(256 * 256 * 4);
    P.wvwT[l]  = (float*)alc(256 * 256 * 4);
    P.Wq[l]    = (float*)alc(128 * 256 * 4);
    P.B2[l]    = (float*)alc(256 * 256 * 4);
    P.M1[l]    = (float*)alc(256 * 256 * 4);
    P.bq[l]    = (float*)alc(256 * 4);
    P.bv[l]    = (float*)alc(256 * 4);
    P.WvT[l]   = (bf16*) alc(256 * 256 * 2);
  }
  int* i_ptr = (int*)alc((size_t)(4 * KN + 1) * 4);
  int* i_src = (int*)alc((size_t)4 * KE * 4);
  int* i_cnt = (int*)alc((size_t)4 * KN * 4);
  int* i_cur = (int*)alc((size_t)4 * KN * 4);
  P.cnt = i_cnt;
  if (off > ws_size) return;

  // -------- pre-phase + prep (both layers) --------
  k_pre<<<64, 384, 0, stream>>>(cf, cfw, cfb, htw, htb, f_cfvec, f_duc);
  k_mean<<<1, 128, 0, stream>>>(f_cfvec, f_cfmean);
  k_cfincol<<<KN, 128, 0, stream>>>(f_cfvec, f_cfmean, b_inf);
  k_infstrip<<<192, 256, 0, stream>>>(x, f_duc, b_inf);
  k_smallA<<<256, 384, 0, stream>>>(x, f_cfvec, b_A12);
  k_prep_all<<<dim3(PT5, 1, 2), 256, 0, stream>>>(P);
  k_fold1<<<dim3(641, 1, 2), 256, 0, stream>>>(P);
  k_fold2<<<dim3(513, 1, 2), 256, 0, stream>>>(P);

  // -------- batched CSR --------
  k_countB<<<(4 * KE + 255) / 256, 256, 0, stream>>>(edges, i_cnt);
  k_scan<<<1, 1024, 0, stream>>>(i_cnt, i_ptr, i_cur, 4 * KN);
  k_fillB<<<(4 * KE + 255) / 256, 256, 0, stream>>>(edges, i_cur, i_src);

  // -------- layer 1: low-rank, no expand (aggattn composes from T12) --------
  gemm_mfma_bt<bf16><<<(NBIG / 128) * 2, 256, 0, stream>>>(
      b_A12, P.bigBT[0], nullptr, b_T12, 192, NBIG, 384, NBIG, NBIG / 128);
  gemm_mfma_bt<bf16><<<(NBIG / 128) * 2, 256, 0, stream>>>(
      b_inf + (size_t)8192 * 384, P.bigBT[0], P.biasc[0],
      b_big + (size_t)8192 * NBIG, 192, NBIG, 384, NBIG, NBIG / 128);
  k_aggattn_lr<<<KN, 256, 0, stream>>>(i_ptr, i_src, b_big, b_T12, P.biasc[0], gbp[0], b_rbar);
  gemm_mfma_bt<bf16><<<2 * 66, 256, 0, stream>>>(
      b_rbar, P.WvT[0], P.bv[0], b_inf, KN, 256, 256, 384, 2);

  // -------- layer 2: full megaGEMM --------
  gemm_mfma_bt<bf16><<<(NBIG / 128) * 66, 256, 0, stream>>>(
      b_inf, P.bigBT[1], P.biasc[1], b_big, KN, NBIG, 384, NBIG, NBIG / 128);
  k_aggattn_pl<<<KN, 256, 0, stream>>>(i_ptr, i_src, b_big, gbp[1], b_rbar);
  gemm_mfma_bt<float><<<2 * 66, 256, 0, stream>>>(
      b_rbar, P.WvT[1], P.bv[1], (float*)d_out, KN, 256, 256, 256, 2);
}